// Round 7
// baseline (11371.110 us; speedup 1.0000x reference)
//
#include <hip/hip_runtime.h>
#include <cmath>

// IDIM=256, CDIM=512, NH=2, N=128, M=64, T=64, BSZ=128
// x(t) = [emb(256) | reads0(64) | reads1(64) | h(512)], K=896, gate rows 2048.
//
// k-major x buffers (float4-packed over k):
//   embsT  [64 t][64 k4][128 b][4]
//   stateT [2 parity][160 ks][128 b][4]  ks 0..31 = reads, 32..159 = h
//   kA(t)/proj/memops read parity t&1 / write (t+1)&1 as noted.
//
// ---- ws float offsets ----
#define WS_EMBT  0                       // 2,097,152
#define WS_STATE 2097152                 //   163,840 (2 x 81,920)
#define WS_C     2260992                 //    65,536  c[b][512]
#define WS_MEM   2326528                 // 1,048,576  mem[b][128][64]
#define WS_RW    3375104                 //    32,768  [hi][b][128]
#define WS_WWS   3407872                 //    32,768
#define WS_PART  3440640                 //   557,056  part2 [8][128][544]
// total 3,997,696 floats (~16 MB)

// kA LDS: W [16][225] f4 (57600B) + x [2][1792] f4 (57344B) + gx 4096B + bias 64B
#define KA_LDS_FLOATS (14400 + 14336 + 1024 + 16)
#define KA_LDS_BYTES  (KA_LDS_FLOATS * 4)

__device__ __forceinline__ float sigm(float x) { return 1.0f / (1.0f + expf(-x)); }
__device__ __forceinline__ float softplusf(float x) {
    return fmaxf(x, 0.0f) + log1pf(expf(-fabsf(x)));
}

// x-slot load: slot f of chunk c (k4g = c*28 + f>>6, b = half*64 + (f&63))
__device__ __forceinline__ float4 ldx(const float* __restrict__ embsT,
                                      const float* __restrict__ stateT,
                                      int c, int f, int half)
{
    int k4g = c * 28 + (f >> 6);
    int b   = half * 64 + (f & 63);
    const float* src = (k4g < 64) ? &embsT[(size_t)k4g * 512 + b * 4]
                                  : &stateT[(size_t)(k4g - 64) * 512 + b * 4];
    return *(const float4*)src;
}

// ---------------- one-time: transpose embs to k-major f4-packed ----------------
__global__ __launch_bounds__(256) void k_embT(const float* __restrict__ embs,
                                              float* __restrict__ ws)
{
    int f4 = blockIdx.x * 256 + threadIdx.x;        // 524288 float4s
    int k4 = f4 & 63, b = (f4 >> 6) & 127, t = f4 >> 13;
    float4 v = *(const float4*)&embs[(size_t)(t * 128 + b) * 256 + k4 * 4];
    *(float4*)&ws[WS_EMBT + ((size_t)(t * 64 + k4) * 128 + b) * 4] = v;
}

// ---------------- one-time: init state ----------------
__global__ __launch_bounds__(256) void k_init(float* __restrict__ ws,
                                              const float* __restrict__ mem_bias,
                                              const float* __restrict__ h0,
                                              const float* __restrict__ c0,
                                              const float* __restrict__ r0)
{
    int i = blockIdx.x * 256 + threadIdx.x;          // 1,261,568 total
    if (i < 81920) {                                  // stateT parity 0
        int ks = i >> 9, c4 = i & 3;
        int k = ks * 4 + c4;
        ws[WS_STATE + i] = (ks < 32) ? r0[k] : h0[k - 128];
        return;
    }
    int j = i - 81920;
    if (j < 65536) { ws[WS_C + j] = c0[j & 511]; return; }         // c[b][ch]
    j -= 65536;
    if (j < 1048576) { ws[WS_MEM + j] = mem_bias[j & 8191]; return; }
    j -= 1048576;
    ws[WS_RW + j] = 0.0f;                                          // rw + wws
}

// ---------------- kA: fused gates GEMM + LSTM pointwise ----------------
// grid 256: ct = bid&127 (4 channels -> 16 gate rows), half = bid>>7 (64 batches).
// ct and ct+128 land on the SAME XCD -> gate-W tile stays L2-resident across steps.
// 512 thr; wave wid: wr=wid>>2 (row grp of 8), wb=wid&3 (batch grp of 16).
// Lane: rl=lane>>4 (row pair), bl=lane&15. Lane computes 2 rows x 1 batch.
// K=896 as 8 chunks of 28 k4; x double-buffered in LDS, prefetch via NAMED regs
// (q0..q3 — no arrays/lambdas: R6's pf[4]-in-lambda spilled to scratch, 440MB/disp).
__global__ void __launch_bounds__(512, 2) k_gates_lstm(
    const float* __restrict__ W_ih,   // (2048,384)
    const float* __restrict__ W_hh,   // (2048,512)
    const float* __restrict__ b_ih,
    const float* __restrict__ b_hh,
    float* __restrict__ ws,
    float* __restrict__ d_out,
    const int* __restrict__ lens,
    int t)
{
    extern __shared__ float sm[];
    float4* w_s4 = (float4*)sm;                 // [16 rows][225 k4] (padded)
    float4* x_s4 = (float4*)(sm + 14400);       // [2 buf][28 k4][64 b]
    float*  gx   = sm + 28736;                  // [16 rows][64 b]
    float*  bias = sm + 29760;                  // [16]

    const int tx = threadIdx.x;
    const int ct = blockIdx.x & 127, half = blockIdx.x >> 7;
    const int ch0 = ct * 4;
    const int p0 = t & 1, p1 = (t + 1) & 1;

    // stage W: 16 rows x 224 f4, row = gate*512 + ch0 + ch_l, lds_row = ch_l*4+gate
#pragma unroll
    for (int i = 0; i < 7; ++i) {
        int f = i * 512 + tx;                   // 0..3583
        int lr = f / 224, k4 = f - lr * 224;
        int grow = (lr & 3) * 512 + ch0 + (lr >> 2);
        int kg = k4 * 4;
        float4 v = (kg < 384) ? *(const float4*)&W_ih[grow * 384 + kg]
                              : *(const float4*)&W_hh[grow * 512 + kg - 384];
        w_s4[lr * 225 + k4] = v;
    }
    if (tx < 16) {
        int grow = (tx & 3) * 512 + ch0 + (tx >> 2);
        bias[tx] = b_ih[grow] + b_hh[grow];
    }

    const float* embsT  = ws + WS_EMBT + (size_t)t * 32768;
    const float* stateT = ws + WS_STATE + (size_t)p0 * 81920;
    const bool   has3   = (tx < 256);           // slot 1536+tx exists iff tx<256

    // prologue: stage chunk 0 into buf 0 (straight-line, named regs)
    {
        float4 q0 = ldx(embsT, stateT, 0, tx, half);
        float4 q1 = ldx(embsT, stateT, 0, 512 + tx, half);
        float4 q2 = ldx(embsT, stateT, 0, 1024 + tx, half);
        float4 q3 = make_float4(0.f, 0.f, 0.f, 0.f);
        if (has3) q3 = ldx(embsT, stateT, 0, 1536 + tx, half);
        x_s4[tx] = q0;
        x_s4[512 + tx] = q1;
        x_s4[1024 + tx] = q2;
        if (has3) x_s4[1536 + tx] = q3;
    }
    __syncthreads();

    const int lane = tx & 63, wid = tx >> 6;
    const int wr = wid >> 2, wb = wid & 3;
    const int rl = lane >> 4, bl = lane & 15;
    const int ra = wr * 8 + rl * 2;             // lds rows ra, ra+1
    const int xoff = wb * 16 + bl;              // batch slot 0..63

    const float4* wa  = w_s4 + ra * 225;
    const float4* wbp = w_s4 + (ra + 1) * 225;

    float acc0 = 0.f, acc1 = 0.f;
    int cur = 0;
    for (int c = 0; c < 8; ++c) {
        // issue prefetch of chunk c+1 (latency hides under the FMA loop below)
        float4 q0, q1, q2, q3;
        const bool pf_on = (c < 7);
        if (pf_on) {
            q0 = ldx(embsT, stateT, c + 1, tx, half);
            q1 = ldx(embsT, stateT, c + 1, 512 + tx, half);
            q2 = ldx(embsT, stateT, c + 1, 1024 + tx, half);
            q3 = make_float4(0.f, 0.f, 0.f, 0.f);
            if (has3) q3 = ldx(embsT, stateT, c + 1, 1536 + tx, half);
        }
        const float4* xb = x_s4 + cur * 1792;
#pragma unroll
        for (int k4 = 0; k4 < 28; ++k4) {
            float4 xv = xb[k4 * 64 + xoff];
            float4 w0 = wa[c * 28 + k4];
            float4 w1 = wbp[c * 28 + k4];
            acc0 += w0.x * xv.x + w0.y * xv.y + w0.z * xv.z + w0.w * xv.w;
            acc1 += w1.x * xv.x + w1.y * xv.y + w1.z * xv.z + w1.w * xv.w;
        }
        if (pf_on) {
            float4* xd = x_s4 + (cur ^ 1) * 1792;
            xd[tx] = q0;
            xd[512 + tx] = q1;
            xd[1024 + tx] = q2;
            if (has3) xd[1536 + tx] = q3;
            __syncthreads();
            cur ^= 1;
        }
    }

    // gate exchange + LSTM pointwise
    gx[ra * 64 + xoff]       = acc0;
    gx[(ra + 1) * 64 + xoff] = acc1;
    __syncthreads();
    if (tx < 256) {
        int ch_l = tx & 3, b_loc = tx >> 2;
        int b = half * 64 + b_loc;
        int ch = ch0 + ch_l;
        float gi = gx[(ch_l * 4 + 0) * 64 + b_loc] + bias[ch_l * 4 + 0];
        float gf = gx[(ch_l * 4 + 1) * 64 + b_loc] + bias[ch_l * 4 + 1];
        float gg = gx[(ch_l * 4 + 2) * 64 + b_loc] + bias[ch_l * 4 + 2];
        float go = gx[(ch_l * 4 + 3) * 64 + b_loc] + bias[ch_l * 4 + 3];
        float* cp = ws + WS_C + b * 512 + ch;
        float c_old = *cp;
        float c_new = sigm(gf) * c_old + sigm(gi) * tanhf(gg);
        float h_new = sigm(go) * tanhf(c_new);
        *cp = c_new;
        ws[WS_STATE + (size_t)p1 * 81920 + (32 + ct) * 512 + b * 4 + ch_l] = h_new;
        d_out[((size_t)t * 128 + b) * 640 + ch] = h_new;
        if (lens[b] - 1 == t) {
            d_out[5242880 + b * 512 + ch] = h_new;
            d_out[5308416 + b * 512 + ch] = c_new;
        }
    }
}

// ---------------- head projections GEMV-GEMM ----------------
// grid 272 = 34 j-tiles(16) x 8 k-chunks(64); 256 thr. Reads h(t) = parity (t+1)&1.
__global__ __launch_bounds__(256) void k_proj(
    const float* __restrict__ ws_c,
    const float* __restrict__ Wr,     // (2,70,512)
    const float* __restrict__ Ww,     // (2,198,512)
    float* __restrict__ part2,        // [kz][b][544]
    int t)
{
    __shared__ float w_s[16 * 64];        // 4KB
    __shared__ float x_s[16 * 128 * 4];   // 32KB
    float4* w_s4 = (float4*)w_s;
    float4* x_s4 = (float4*)x_s;

    const int tx = threadIdx.x;
    const int jt = blockIdx.x >> 3, kz = blockIdx.x & 7;
    const int j0 = jt * 16, k0 = kz * 64;
    const float* stateT = ws_c + WS_STATE + (size_t)((t + 1) & 1) * 81920;

    {
        int rl = tx >> 4, kq = tx & 15;
        int j = j0 + rl;
        float4 v = make_float4(0.f, 0.f, 0.f, 0.f);
        if (j < 536) {
            int hi = j >= 268, q = j - hi * 268;
            v = (q < 70) ? *(const float4*)&Wr[(hi * 70 + q) * 512 + k0 + kq * 4]
                         : *(const float4*)&Ww[(hi * 198 + (q - 70)) * 512 + k0 + kq * 4];
        }
        w_s4[tx] = v;
    }
#pragma unroll
    for (int it = 0; it < 8; ++it) {
        int f = it * 256 + tx;
        int k4 = f >> 7, b = f & 127;
        x_s4[f] = *(const float4*)&stateT[(size_t)(32 + kz * 16 + k4) * 512 + b * 4];
    }
    __syncthreads();

    const int lane = tx & 63, wid = tx >> 6;
    const int jw0 = wid * 4;
    float acc0[4] = {}, acc1[4] = {};
#pragma unroll 4
    for (int k4 = 0; k4 < 16; ++k4) {
        float4 xv0 = x_s4[k4 * 128 + lane];
        float4 xv1 = x_s4[k4 * 128 + 64 + lane];
#pragma unroll
        for (int r = 0; r < 4; ++r) {
            float4 wv = w_s4[(jw0 + r) * 16 + k4];
            acc0[r] += wv.x * xv0.x + wv.y * xv0.y + wv.z * xv0.z + wv.w * xv0.w;
            acc1[r] += wv.x * xv1.x + wv.y * xv1.y + wv.z * xv1.z + wv.w * xv1.w;
        }
    }
#pragma unroll
    for (int r = 0; r < 4; ++r) {
        int j = j0 + jw0 + r;
        if (j < 536) {
            part2[(size_t)kz * 69632 + lane * 544 + j]        = acc0[r];
            part2[(size_t)kz * 69632 + (lane + 64) * 544 + j] = acc1[r];
        }
    }
}

// ---------------- per-batch NTM memory ops ----------------
__global__ __launch_bounds__(256) void k_memops(
    const float* __restrict__ part2,  // [8][128][544]
    const float* __restrict__ br,     // (2,70)
    const float* __restrict__ bw,     // (2,198)
    float* __restrict__ ws,
    float* __restrict__ d_out,
    int t)
{
    const int b = blockIdx.x;
    const int tx = threadIdx.x;
    const int lx = tx & 127;
    const int grp = tx >> 7;          // 0 = read head, 1 = write head
    const int wid = tx >> 6;

    __shared__ float mem_s[128 * 66];
    __shared__ float proj_s[544];
    __shared__ float wg2_s[2 * 128];
    __shared__ float wf_s[2 * 128];
    __shared__ float red_s[16];
    __shared__ float ea_s[128];
    __shared__ float rvp_s[4 * 66];

    float* memg   = ws + WS_MEM;
    float* stateT = ws + WS_STATE + (size_t)((t + 1) & 1) * 81920;
    float* rwg    = ws + WS_RW;
    float* wwsg   = ws + WS_WWS;

    for (int j = tx; j < 536; j += 256) {
        int hi = j >= 268, q = j - hi * 268;
        float s = (q < 70) ? br[hi * 70 + q] : bw[hi * 198 + (q - 70)];
#pragma unroll
        for (int kzq = 0; kzq < 8; ++kzq)
            s += part2[(size_t)kzq * 69632 + b * 544 + j];
        proj_s[j] = s;
    }
#pragma unroll
    for (int e = 0; e < 8; ++e) {
        int f4 = e * 256 + tx;
        int n = f4 >> 4, m4 = (f4 & 15) * 4;
        float4 v = *(const float4*)&memg[b * 8192 + f4 * 4];
        *(float2*)&mem_s[n * 66 + m4]     = make_float2(v.x, v.y);
        *(float2*)&mem_s[n * 66 + m4 + 2] = make_float2(v.z, v.w);
    }
    __syncthreads();

    for (int hi = 0; hi < 2; ++hi) {
        const float* p = proj_s + hi * 268 + grp * 70;
        float* wprev_g = (grp == 0 ? rwg : wwsg) + (hi * 128 + b) * 128;

        float beta = softplusf(p[64]);
        float g = sigm(p[65]);
        float s0 = p[66], s1 = p[67], s2 = p[68];
        float sm = fmaxf(s0, fmaxf(s1, s2));
        float e0 = expf(s0 - sm), e1 = expf(s1 - sm), e2 = expf(s2 - sm);
        float sden = e0 + e1 + e2;
        s0 = e0 / sden; s1 = e1 / sden; s2 = e2 / sden;
        float gamma = 1.0f + softplusf(p[69]);

        const float* mrow = mem_s + lx * 66;
        float dot = 0.f, nm = 0.f, nk = 0.f;
#pragma unroll
        for (int m = 0; m < 64; m += 2) {
            float2 kv2 = *(const float2*)&p[m];
            float2 mv2 = *(const float2*)&mrow[m];
            float kx = kv2.x + 1e-16f, ky = kv2.y + 1e-16f;
            float mx = mv2.x + 1e-16f, my = mv2.y + 1e-16f;
            dot += mx * kx + my * ky;
            nm  += mx * mx + my * my;
            nk  += kx * kx + ky * ky;
        }
        float sim = dot / fmaxf(sqrtf(nm) * sqrtf(nk), 1e-8f);
        float z = beta * sim;

        float r = z;
#pragma unroll
        for (int d = 32; d > 0; d >>= 1) r = fmaxf(r, __shfl_xor(r, d));
        if ((tx & 63) == 0) red_s[wid] = r;
        __syncthreads();
        float zmax = fmaxf(red_s[grp * 2], red_s[grp * 2 + 1]);
        float ez = expf(z - zmax);
        r = ez;
#pragma unroll
        for (int d = 32; d > 0; d >>= 1) r += __shfl_xor(r, d);
        if ((tx & 63) == 0) red_s[8 + wid] = r;
        __syncthreads();
        float zsum = red_s[8 + grp * 2] + red_s[8 + grp * 2 + 1];
        float wc = ez / zsum;
        float wgv = g * wc + (1.f - g) * wprev_g[lx];
        wg2_s[grp * 128 + lx] = wgv;
        __syncthreads();
        float wwv = s0 * wg2_s[grp * 128 + ((lx + 127) & 127)] + s1 * wgv
                  + s2 * wg2_s[grp * 128 + ((lx + 1) & 127)];
        float wp = powf(wwv, gamma);
        r = wp;
#pragma unroll
        for (int d = 32; d > 0; d >>= 1) r += __shfl_xor(r, d);
        if ((tx & 63) == 0) red_s[wid] = r;
        __syncthreads();
        float psum = red_s[grp * 2] + red_s[grp * 2 + 1];
        float wfin = wp / (psum + 1e-16f);
        wf_s[grp * 128 + lx] = wfin;
        wprev_g[lx] = wfin;
        __syncthreads();

        {
            int m = tx & 63, p4 = tx >> 6;
            float rv = 0.f;
            const int nb = p4 * 32;
#pragma unroll
            for (int n8 = 0; n8 < 32; ++n8) {
                int n = nb + n8;
                rv += wf_s[n] * mem_s[n * 66 + m];
            }
            rvp_s[p4 * 66 + m] = rv;
        }
        if (tx < 64)        ea_s[tx] = sigm(proj_s[hi * 268 + 140 + tx]);
        else if (tx < 128)  ea_s[tx] = proj_s[hi * 268 + 204 + (tx - 64)];
        __syncthreads();

        if (tx < 64) {
            float rvf = rvp_s[tx] + rvp_s[66 + tx] + rvp_s[132 + tx] + rvp_s[198 + tx];
            stateT[((hi * 64 + tx) >> 2) * 512 + b * 4 + (tx & 3)] = rvf;
            d_out[((size_t)t * 128 + b) * 640 + 512 + hi * 64 + tx] = rvf;
        }
#pragma unroll
        for (int e = 0; e < 16; ++e) {
            int f = e * 256 + tx;
            int n = f >> 5, m2 = (f & 31) * 2;
            float w2 = wf_s[128 + n];
            float2 mv = *(const float2*)&mem_s[n * 66 + m2];
            mv.x = mv.x * (1.f - w2 * ea_s[m2])     + w2 * ea_s[64 + m2];
            mv.y = mv.y * (1.f - w2 * ea_s[m2 + 1]) + w2 * ea_s[65 + m2];
            *(float2*)&mem_s[n * 66 + m2] = mv;
            if (hi == 1) *(float2*)&memg[b * 8192 + f * 2] = mv;
        }
        __syncthreads();
    }
}

// ---------------- host ----------------
extern "C" void kernel_launch(void* const* d_in, const int* in_sizes, int n_in,
                              void* d_out, int out_size, void* d_ws, size_t ws_size,
                              hipStream_t stream)
{
    (void)in_sizes; (void)n_in; (void)out_size; (void)ws_size;
    const float* embs     = (const float*)d_in[0];
    const int*   lens     = (const int*)  d_in[1];
    const float* mem_bias = (const float*)d_in[2];
    const float* W_ih     = (const float*)d_in[3];
    const float* W_hh     = (const float*)d_in[4];
    const float* b_ih     = (const float*)d_in[5];
    const float* b_hh     = (const float*)d_in[6];
    const float* Wr       = (const float*)d_in[7];
    const float* br       = (const float*)d_in[8];
    const float* Ww       = (const float*)d_in[9];
    const float* bw       = (const float*)d_in[10];
    const float* h0       = (const float*)d_in[11];
    const float* c0       = (const float*)d_in[12];
    const float* r0       = (const float*)d_in[13];
    float* out = (float*)d_out;
    float* ws  = (float*)d_ws;
    float* part2 = ws + WS_PART;

    hipFuncSetAttribute(reinterpret_cast<const void*>(&k_gates_lstm),
                        hipFuncAttributeMaxDynamicSharedMemorySize, KA_LDS_BYTES);

    k_embT<<<2048, 256, 0, stream>>>(embs, ws);
    k_init<<<4928, 256, 0, stream>>>(ws, mem_bias, h0, c0, r0);
    for (int t = 0; t < 64; ++t) {
        k_gates_lstm<<<256, 512, KA_LDS_BYTES, stream>>>(W_ih, W_hh, b_ih, b_hh,
                                                         ws, out, lens, t);
        k_proj<<<272, 256, 0, stream>>>(ws, Wr, Ww, part2, t);
        k_memops<<<128, 256, 0, stream>>>(part2, br, bw, ws, out, t);
    }
}

// Round 8
// 2675.411 us; speedup vs baseline: 4.2502x; 4.2502x over previous
//
#include <hip/hip_runtime.h>
#include <cmath>

// IDIM=256, CDIM=512, NH=2, N=128, M=64, T=64, BSZ=128
// x(t) = [emb(256) | reads0(64) | reads1(64) | h(512)], K=896, gate rows 2048.
// GEMV-style: lane = batch (2 per lane), weights broadcast from LDS.
// R8 = R5 structure; k_gates staging converted to global_load_lds DMA
// (no VGPR round-trip — kills the R6/R7 scratch-traffic failure mode).
//
// k-major x buffers (float4-packed over k):
//   embsT  [64 t][64 k4][128 b][4]
//   stateT [160 ks][128 b][4]   ks 0..31 = reads (k 256..383), 32..159 = h
//
// ---- ws float offsets ----
#define WS_EMBT  0                       // 2,097,152
#define WS_STATE 2097152                 //    81,920
#define WS_C     2179072                 //    65,536  c[ch][b]
#define WS_MEM   2244608                 // 1,048,576  mem[b][128][64]
#define WS_RW    3293184                 //    32,768  [hi][b][128]
#define WS_WWS   3325952                 //    32,768
#define WS_PART  3358720                 // 2,097,152  partials [8][2048][128]
                                         //            part2 [8][128][544] aliases
// total 5,455,872 floats (~21.9 MB)

#define GATES_LDS_BYTES ((3584 + 14336) * 4)   // W 14KB + x 57.3KB = 71.7KB

// direct global->LDS 16B DMA; lds base must be wave-uniform (lane i lands at
// base + i*16). Slot layouts below are lane-linear by construction.
#define GLD16(g, l) __builtin_amdgcn_global_load_lds( \
    (const __attribute__((address_space(1))) void*)(g), \
    (__attribute__((address_space(3))) void*)(l), 16, 0, 0)

__device__ __forceinline__ float sigm(float x) { return 1.0f / (1.0f + expf(-x)); }
__device__ __forceinline__ float softplusf(float x) {
    return fmaxf(x, 0.0f) + log1pf(expf(-fabsf(x)));
}

// ---------------- one-time: transpose embs to k-major f4-packed ----------------
__global__ __launch_bounds__(256) void k_embT(const float* __restrict__ embs,
                                              float* __restrict__ ws)
{
    int f4 = blockIdx.x * 256 + threadIdx.x;        // 524288 float4s
    int k4 = f4 & 63, b = (f4 >> 6) & 127, t = f4 >> 13;
    float4 v = *(const float4*)&embs[(size_t)(t * 128 + b) * 256 + k4 * 4];
    *(float4*)&ws[WS_EMBT + ((size_t)(t * 64 + k4) * 128 + b) * 4] = v;
}

// ---------------- one-time: init state ----------------
__global__ __launch_bounds__(256) void k_init(float* __restrict__ ws,
                                              const float* __restrict__ mem_bias,
                                              const float* __restrict__ h0,
                                              const float* __restrict__ c0,
                                              const float* __restrict__ r0)
{
    int i = blockIdx.x * 256 + threadIdx.x;          // 1,261,568 total
    if (i < 81920) {                                  // stateT
        int ks = i >> 9, rem = i & 511, c4 = rem & 3;
        int k = ks * 4 + c4;
        ws[WS_STATE + i] = (ks < 32) ? r0[k] : h0[k - 128];
        return;
    }
    int j = i - 81920;
    if (j < 65536) { ws[WS_C + j] = c0[j >> 7]; return; }          // c[ch][b]
    j -= 65536;
    if (j < 1048576) { ws[WS_MEM + j] = mem_bias[j & 8191]; return; }
    j -= 1048576;
    ws[WS_RW + j] = 0.0f;                                          // rw + wws
}

// ---------------- gates GEMV-GEMM ----------------
// grid 512 = 64 row-tiles(32) x 8 k-chunks(112); 256 thr; 2 blocks/CU.
// wave wid: rows wid*8..wid*8+7; each lane handles batches (lane, lane+64).
// W and the x-slice staged to LDS via global_load_lds; inner loop pure LDS+FMA.
__global__ void __launch_bounds__(256, 2) k_gates(
    const float* __restrict__ W_ih,   // (2048,384)
    const float* __restrict__ W_hh,   // (2048,512)
    const float* __restrict__ ws_c,
    float* __restrict__ partials,
    int t)
{
    extern __shared__ float sm[];
    float4* w_s4 = (float4*)sm;              // [32 rows][28 kq]
    float4* x_s4 = (float4*)(sm + 3584);     // [28 k4][128 b]

    const int tx = threadIdx.x;
    const int rt = blockIdx.x >> 3, kz = blockIdx.x & 7;
    const int r0g = rt * 32, k0 = kz * 112;
    const int lane = tx & 63, wid = tx >> 6;

    const float* embsT  = ws_c + WS_EMBT + (size_t)t * 32768;
    const float* stateT = ws_c + WS_STATE;

    // stage W: 896 f4 ([32 rows][28 kq]), slot f = it*256+tx (lane-linear)
#pragma unroll
    for (int it = 0; it < 3; ++it) {
        int f = it * 256 + tx;
        int rl = f / 28, kq = f - rl * 28;
        int kg = k0 + kq * 4, r = r0g + rl;
        const float* gp = (kg < 384) ? &W_ih[r * 384 + kg]
                                     : &W_hh[r * 512 + (kg - 384)];
        GLD16(gp, &w_s4[it * 256 + wid * 64]);
    }
    if (tx < 128) {                           // slots 768..895 (waves 0,1 only)
        int f = 768 + tx;
        int rl = f / 28, kq = f - rl * 28;
        int kg = k0 + kq * 4, r = r0g + rl;
        const float* gp = (kg < 384) ? &W_ih[r * 384 + kg]
                                     : &W_hh[r * 512 + (kg - 384)];
        GLD16(gp, &w_s4[768 + wid * 64]);
    }
    // stage x: 3584 f4 ([28 k4][128 b]), slot f = it*256+tx (lane-linear)
#pragma unroll
    for (int it = 0; it < 14; ++it) {
        int f = it * 256 + tx;
        int k4g = kz * 28 + (f >> 7);
        int b = f & 127;
        const float* gp = (k4g < 64) ? &embsT[(size_t)k4g * 512 + b * 4]
                                     : &stateT[(size_t)(k4g - 64) * 512 + b * 4];
        GLD16(gp, &x_s4[it * 256 + wid * 64]);
    }
    __syncthreads();                          // compiler drains vmcnt before barrier

    const int wr0 = wid * 8;
    float acc0[8] = {}, acc1[8] = {};
#pragma unroll 4
    for (int k4 = 0; k4 < 28; ++k4) {
        float4 xv0 = x_s4[k4 * 128 + lane];
        float4 xv1 = x_s4[k4 * 128 + 64 + lane];
#pragma unroll
        for (int r = 0; r < 8; ++r) {
            float4 wv = w_s4[(wr0 + r) * 28 + k4];
            acc0[r] += wv.x * xv0.x + wv.y * xv0.y + wv.z * xv0.z + wv.w * xv0.w;
            acc1[r] += wv.x * xv1.x + wv.y * xv1.y + wv.z * xv1.z + wv.w * xv1.w;
        }
    }
#pragma unroll
    for (int r = 0; r < 8; ++r) {
        int row = r0g + wr0 + r;
        partials[(size_t)kz * 262144 + row * 128 + lane]      = acc0[r];
        partials[(size_t)kz * 262144 + row * 128 + 64 + lane] = acc1[r];
    }
}

// ---------------- LSTM pointwise ----------------
// grid 256 = 128 ch-tiles(4) x 2 batch-halves; wave w -> ch = cht*4 + w.
__global__ __launch_bounds__(256) void k_lstm(
    const float* __restrict__ partials,
    const float* __restrict__ b_ih,
    const float* __restrict__ b_hh,
    float* __restrict__ ws,
    float* __restrict__ d_out,
    const int* __restrict__ lens,
    int t)
{
    const int tx = threadIdx.x;
    const int half = blockIdx.x & 1, cht = blockIdx.x >> 1;
    const int ch = cht * 4 + (tx >> 6);
    const int lane = tx & 63, b = half * 64 + lane;

    float g4[4];
#pragma unroll
    for (int g = 0; g < 4; ++g) {
        int r = g * 512 + ch;
        float s = b_ih[r] + b_hh[r];
#pragma unroll
        for (int kzq = 0; kzq < 8; ++kzq)
            s += partials[(size_t)kzq * 262144 + r * 128 + b];
        g4[g] = s;
    }
    float* cp = ws + WS_C + ch * 128;
    float c_old = cp[b];
    float c_new = sigm(g4[1]) * c_old + sigm(g4[0]) * tanhf(g4[2]);
    float h_new = sigm(g4[3]) * tanhf(c_new);
    cp[b] = c_new;
    ws[WS_STATE + (32 + (ch >> 2)) * 512 + b * 4 + (ch & 3)] = h_new;
    d_out[((size_t)t * 128 + b) * 640 + ch] = h_new;
    if (lens[b] - 1 == t) {
        d_out[5242880 + b * 512 + ch] = h_new;
        d_out[5308416 + b * 512 + ch] = c_new;
    }
}

// ---------------- head projections GEMV-GEMM ----------------
// grid 272 = 34 j-tiles(16) x 8 k-chunks(64); 256 thr.
// wave wid: j rows wid*4..+3; lane batches (lane, lane+64). Bulk LDS staging.
__global__ __launch_bounds__(256) void k_proj(
    const float* __restrict__ ws_c,
    const float* __restrict__ Wr,     // (2,70,512)
    const float* __restrict__ Ww,     // (2,198,512)
    float* __restrict__ part2)        // [kz][b][544]
{
    __shared__ float w_s[16 * 64];        // 4KB
    __shared__ float x_s[16 * 128 * 4];   // 32KB
    float4* w_s4 = (float4*)w_s;
    float4* x_s4 = (float4*)x_s;

    const int tx = threadIdx.x;
    const int jt = blockIdx.x >> 3, kz = blockIdx.x & 7;
    const int j0 = jt * 16, k0 = kz * 64;
    const float* stateT = ws_c + WS_STATE;

    // stage W: 256 f4 (16 j x 16 kq)
    {
        int rl = tx >> 4, kq = tx & 15;
        int j = j0 + rl;
        float4 v = make_float4(0.f, 0.f, 0.f, 0.f);
        if (j < 536) {
            int hi = j >= 268, q = j - hi * 268;
            v = (q < 70) ? *(const float4*)&Wr[(hi * 70 + q) * 512 + k0 + kq * 4]
                         : *(const float4*)&Ww[(hi * 198 + (q - 70)) * 512 + k0 + kq * 4];
        }
        w_s4[tx] = v;
    }
    // stage x: 2048 f4 ([16 k4][128 b]) from h part of stateT
#pragma unroll
    for (int it = 0; it < 8; ++it) {
        int f = it * 256 + tx;
        int k4 = f >> 7, b = f & 127;
        x_s4[f] = *(const float4*)&stateT[(size_t)(32 + kz * 16 + k4) * 512 + b * 4];
    }
    __syncthreads();

    const int lane = tx & 63, wid = tx >> 6;
    const int jw0 = wid * 4;
    float acc0[4] = {}, acc1[4] = {};
#pragma unroll 4
    for (int k4 = 0; k4 < 16; ++k4) {
        float4 xv0 = x_s4[k4 * 128 + lane];
        float4 xv1 = x_s4[k4 * 128 + 64 + lane];
#pragma unroll
        for (int r = 0; r < 4; ++r) {
            float4 wv = w_s4[(jw0 + r) * 16 + k4];
            acc0[r] += wv.x * xv0.x + wv.y * xv0.y + wv.z * xv0.z + wv.w * xv0.w;
            acc1[r] += wv.x * xv1.x + wv.y * xv1.y + wv.z * xv1.z + wv.w * xv1.w;
        }
    }
#pragma unroll
    for (int r = 0; r < 4; ++r) {
        int j = j0 + jw0 + r;
        if (j < 536) {
            part2[(size_t)kz * 69632 + lane * 544 + j]        = acc0[r];
            part2[(size_t)kz * 69632 + (lane + 64) * 544 + j] = acc1[r];
        }
    }
}

// ---------------- per-batch NTM memory ops ----------------
__global__ __launch_bounds__(256) void k_memops(
    const float* __restrict__ part2,  // [8][128][544]
    const float* __restrict__ br,     // (2,70)
    const float* __restrict__ bw,     // (2,198)
    float* __restrict__ ws,
    float* __restrict__ d_out,
    int t)
{
    const int b = blockIdx.x;
    const int tx = threadIdx.x;
    const int lx = tx & 127;
    const int grp = tx >> 7;          // 0 = read head, 1 = write head
    const int wid = tx >> 6;

    __shared__ float mem_s[128 * 66];
    __shared__ float proj_s[544];
    __shared__ float wg2_s[2 * 128];
    __shared__ float wf_s[2 * 128];
    __shared__ float red_s[16];
    __shared__ float ea_s[128];
    __shared__ float rvp_s[4 * 66];

    float* memg   = ws + WS_MEM;
    float* stateT = ws + WS_STATE;
    float* rwg    = ws + WS_RW;
    float* wwsg   = ws + WS_WWS;

    for (int j = tx; j < 536; j += 256) {
        int hi = j >= 268, q = j - hi * 268;
        float s = (q < 70) ? br[hi * 70 + q] : bw[hi * 198 + (q - 70)];
#pragma unroll
        for (int kzq = 0; kzq < 8; ++kzq)
            s += part2[(size_t)kzq * 69632 + b * 544 + j];
        proj_s[j] = s;
    }
#pragma unroll
    for (int e = 0; e < 8; ++e) {
        int f4 = e * 256 + tx;
        int n = f4 >> 4, m4 = (f4 & 15) * 4;
        float4 v = *(const float4*)&memg[b * 8192 + f4 * 4];
        *(float2*)&mem_s[n * 66 + m4]     = make_float2(v.x, v.y);
        *(float2*)&mem_s[n * 66 + m4 + 2] = make_float2(v.z, v.w);
    }
    __syncthreads();

    for (int hi = 0; hi < 2; ++hi) {
        const float* p = proj_s + hi * 268 + grp * 70;
        float* wprev_g = (grp == 0 ? rwg : wwsg) + (hi * 128 + b) * 128;

        float beta = softplusf(p[64]);
        float g = sigm(p[65]);
        float s0 = p[66], s1 = p[67], s2 = p[68];
        float sm = fmaxf(s0, fmaxf(s1, s2));
        float e0 = expf(s0 - sm), e1 = expf(s1 - sm), e2 = expf(s2 - sm);
        float sden = e0 + e1 + e2;
        s0 = e0 / sden; s1 = e1 / sden; s2 = e2 / sden;
        float gamma = 1.0f + softplusf(p[69]);

        const float* mrow = mem_s + lx * 66;
        float dot = 0.f, nm = 0.f, nk = 0.f;
#pragma unroll
        for (int m = 0; m < 64; m += 2) {
            float2 kv2 = *(const float2*)&p[m];
            float2 mv2 = *(const float2*)&mrow[m];
            float kx = kv2.x + 1e-16f, ky = kv2.y + 1e-16f;
            float mx = mv2.x + 1e-16f, my = mv2.y + 1e-16f;
            dot += mx * kx + my * ky;
            nm  += mx * mx + my * my;
            nk  += kx * kx + ky * ky;
        }
        float sim = dot / fmaxf(sqrtf(nm) * sqrtf(nk), 1e-8f);
        float z = beta * sim;

        float r = z;
#pragma unroll
        for (int d = 32; d > 0; d >>= 1) r = fmaxf(r, __shfl_xor(r, d));
        if ((tx & 63) == 0) red_s[wid] = r;
        __syncthreads();
        float zmax = fmaxf(red_s[grp * 2], red_s[grp * 2 + 1]);
        float ez = expf(z - zmax);
        r = ez;
#pragma unroll
        for (int d = 32; d > 0; d >>= 1) r += __shfl_xor(r, d);
        if ((tx & 63) == 0) red_s[8 + wid] = r;
        __syncthreads();
        float zsum = red_s[8 + grp * 2] + red_s[8 + grp * 2 + 1];
        float wc = ez / zsum;
        float wgv = g * wc + (1.f - g) * wprev_g[lx];
        wg2_s[grp * 128 + lx] = wgv;
        __syncthreads();
        float wwv = s0 * wg2_s[grp * 128 + ((lx + 127) & 127)] + s1 * wgv
                  + s2 * wg2_s[grp * 128 + ((lx + 1) & 127)];
        float wp = powf(wwv, gamma);
        r = wp;
#pragma unroll
        for (int d = 32; d > 0; d >>= 1) r += __shfl_xor(r, d);
        if ((tx & 63) == 0) red_s[wid] = r;
        __syncthreads();
        float psum = red_s[grp * 2] + red_s[grp * 2 + 1];
        float wfin = wp / (psum + 1e-16f);
        wf_s[grp * 128 + lx] = wfin;
        wprev_g[lx] = wfin;
        __syncthreads();

        {
            int m = tx & 63, p4 = tx >> 6;
            float rv = 0.f;
            const int nb = p4 * 32;
#pragma unroll
            for (int n8 = 0; n8 < 32; ++n8) {
                int n = nb + n8;
                rv += wf_s[n] * mem_s[n * 66 + m];
            }
            rvp_s[p4 * 66 + m] = rv;
        }
        if (tx < 64)        ea_s[tx] = sigm(proj_s[hi * 268 + 140 + tx]);
        else if (tx < 128)  ea_s[tx] = proj_s[hi * 268 + 204 + (tx - 64)];
        __syncthreads();

        if (tx < 64) {
            float rvf = rvp_s[tx] + rvp_s[66 + tx] + rvp_s[132 + tx] + rvp_s[198 + tx];
            stateT[((hi * 64 + tx) >> 2) * 512 + b * 4 + (tx & 3)] = rvf;
            d_out[((size_t)t * 128 + b) * 640 + 512 + hi * 64 + tx] = rvf;
        }
#pragma unroll
        for (int e = 0; e < 16; ++e) {
            int f = e * 256 + tx;
            int n = f >> 5, m2 = (f & 31) * 2;
            float w2 = wf_s[128 + n];
            float2 mv = *(const float2*)&mem_s[n * 66 + m2];
            mv.x = mv.x * (1.f - w2 * ea_s[m2])     + w2 * ea_s[64 + m2];
            mv.y = mv.y * (1.f - w2 * ea_s[m2 + 1]) + w2 * ea_s[65 + m2];
            *(float2*)&mem_s[n * 66 + m2] = mv;
            if (hi == 1) *(float2*)&memg[b * 8192 + f * 2] = mv;
        }
        __syncthreads();
    }
}

// ---------------- host ----------------
extern "C" void kernel_launch(void* const* d_in, const int* in_sizes, int n_in,
                              void* d_out, int out_size, void* d_ws, size_t ws_size,
                              hipStream_t stream)
{
    (void)in_sizes; (void)n_in; (void)out_size; (void)ws_size;
    const float* embs     = (const float*)d_in[0];
    const int*   lens     = (const int*)  d_in[1];
    const float* mem_bias = (const float*)d_in[2];
    const float* W_ih     = (const float*)d_in[3];
    const float* W_hh     = (const float*)d_in[4];
    const float* b_ih     = (const float*)d_in[5];
    const float* b_hh     = (const float*)d_in[6];
    const float* Wr       = (const float*)d_in[7];
    const float* br       = (const float*)d_in[8];
    const float* Ww       = (const float*)d_in[9];
    const float* bw       = (const float*)d_in[10];
    const float* h0       = (const float*)d_in[11];
    const float* c0       = (const float*)d_in[12];
    const float* r0       = (const float*)d_in[13];
    float* out = (float*)d_out;
    float* ws  = (float*)d_ws;
    float* partials = ws + WS_PART;
    float* part2    = ws + WS_PART;

    hipFuncSetAttribute(reinterpret_cast<const void*>(&k_gates),
                        hipFuncAttributeMaxDynamicSharedMemorySize, GATES_LDS_BYTES);

    k_embT<<<2048, 256, 0, stream>>>(embs, ws);
    k_init<<<4928, 256, 0, stream>>>(ws, mem_bias, h0, c0, r0);
    for (int t = 0; t < 64; ++t) {
        k_gates<<<512, 256, GATES_LDS_BYTES, stream>>>(W_ih, W_hh, ws, partials, t);
        k_lstm<<<256, 256, 0, stream>>>(partials, b_ih, b_hh, ws, out, lens, t);
        k_proj<<<272, 256, 0, stream>>>(ws, Wr, Ww, part2);
        k_memops<<<128, 256, 0, stream>>>(part2, br, bw, ws, out, t);
    }
}